// Round 3
// baseline (174.371 us; speedup 1.0000x reference)
//
#include <hip/hip_runtime.h>
#include <math.h>

#define MARGIN 0.3f
#define NJ 32   // column chunks (grid.y)

typedef short bf16x8 __attribute__((ext_vector_type(8)));
typedef float f32x4 __attribute__((ext_vector_type(4)));

__device__ __forceinline__ unsigned short f2bf_rne(float x) {
    unsigned b = __float_as_uint(x);
    unsigned r = b + 0x7FFFu + ((b >> 16) & 1u);
    return (unsigned short)(r >> 16);
}
__device__ __forceinline__ float bf2f(unsigned short h) {
    return __uint_as_float(((unsigned)h) << 16);
}
// family table {0,1,2,1,3,3} packed 2 bits/entry
__device__ __forceinline__ int fam_of(int lbl) { return (0xF64 >> (2 * lbl)) & 3; }

// ---------------- K1: deterministic counting sort by family ----------------
// 1 block, 1024 threads, 8 rows/thread. Wave-level shfl scans; 3 barriers.
__global__ __launch_bounds__(1024) void sort_kernel(const int* __restrict__ labels,
                                                    int* __restrict__ posOf,
                                                    unsigned char* __restrict__ famSorted,
                                                    int* __restrict__ famLoHi, int B) {
    const int t = threadIdx.x;
    const int lane = t & 63, w = t >> 6;
    int lc[4] = {0, 0, 0, 0};
    int lf[8], lr[8];
#pragma unroll
    for (int j = 0; j < 8; j++) {
        int f = fam_of(labels[t * 8 + j]);
        lf[j] = f; lr[j] = lc[f]++;
    }
    // inclusive scan of per-thread counts across the wave, per family
    int inc[4];
#pragma unroll
    for (int f = 0; f < 4; f++) {
        int v = lc[f];
#pragma unroll
        for (int o = 1; o < 64; o <<= 1) {
            int u = __shfl_up(v, o, 64);
            if (lane >= o) v += u;
        }
        inc[f] = v;
    }
    __shared__ int waveTot[16][4], waveBase[16][4], famBase[4], famTotS[4];
    if (lane == 63)
#pragma unroll
        for (int f = 0; f < 4; f++) waveTot[w][f] = inc[f];
    __syncthreads();
    if (t < 64) {  // wave 0: scan 16 wave-totals for each of 4 families
        int f = t >> 4, ww = t & 15;
        int v = waveTot[ww][f];
#pragma unroll
        for (int o = 1; o < 16; o <<= 1) {
            int u = __shfl_up(v, o, 64);
            if ((t & 15) >= o) v += u;
        }
        waveBase[ww][f] = v - waveTot[ww][f];  // exclusive
        if (ww == 15) famTotS[f] = v;
    }
    __syncthreads();
    if (t == 0) {
        int b = 0;
#pragma unroll
        for (int f = 0; f < 4; f++) {
            famBase[f] = b; famLoHi[f] = b; b += famTotS[f]; famLoHi[4 + f] = b;
        }
    }
    __syncthreads();
    int base[4];
#pragma unroll
    for (int f = 0; f < 4; f++) base[f] = famBase[f] + waveBase[w][f] + (inc[f] - lc[f]);
#pragma unroll
    for (int j = 0; j < 8; j++) {
        int pos = base[lf[j]] + lr[j];
        posOf[t * 8 + j] = pos;
        famSorted[pos] = (unsigned char)lf[j];
    }
}

// ---------------- K2: normalize + bf16 hi/lo split + packed scatter ----------------
// pack layout (bf16 elems): idx = strip*1024 + (k>>3)*128 + (pos&15)*8 + (k&7)
// so lane l reads its MFMA fragment as one coalesced 16B load at strip*1024 + l*8.
__global__ __launch_bounds__(256) void normpack_kernel(const float* __restrict__ emb,
                                                       const int* __restrict__ posOf,
                                                       short* __restrict__ packHi,
                                                       short* __restrict__ packLo, int B) {
    const int lane = threadIdx.x & 63;
    const int wid  = threadIdx.x >> 6;
    const int row  = blockIdx.x * 4 + wid;
    float x = emb[(size_t)row * 64 + lane];
    float ss = x * x;
#pragma unroll
    for (int o = 32; o > 0; o >>= 1) ss += __shfl_xor(ss, o, 64);
    float n = fmaxf(sqrtf(ss), 1e-12f);
    float v = x / n;
    unsigned short h = f2bf_rne(v);
    float lo = v - bf2f(h);
    unsigned short l = f2bf_rne(lo);
    int pos = posOf[row];
    size_t idx = (size_t)(pos >> 4) * 1024 + (size_t)(lane >> 3) * 128 + (size_t)(pos & 15) * 8 + (lane & 7);
    packHi[idx] = (short)h;
    packLo[idx] = (short)l;
}

// ---------------- K3: MFMA GEMM + masked min/max (no LDS, prefetched) ----------------
// 4 waves/block, 64 rows/wave (4 strips of 16), chunk of B/NJ cols.
__global__ __launch_bounds__(256) void gemm_minmax_kernel(
    const short* __restrict__ packHi, const short* __restrict__ packLo,
    const unsigned char* __restrict__ famSorted, const int* __restrict__ famLoHi,
    float* __restrict__ pMin, float* __restrict__ pMax, int B) {
    const int lane = threadIdx.x & 63;
    const int wid  = threadIdx.x >> 6;
    const int g = lane >> 4;
    const int c = lane & 15;
    const int rowBase = blockIdx.x * 256 + wid * 64;
    const int aStrip0 = rowBase >> 4;

    // A fragments: 4 strips x 2 k-windows x (hi,lo). 64 VGPRs, resident all sweep.
    bf16x8 aHi[4][2], aLo[4][2];
#pragma unroll
    for (int s = 0; s < 4; s++) {
        const bf16x8* pH = (const bf16x8*)(packHi + (size_t)(aStrip0 + s) * 1024);
        const bf16x8* pL = (const bf16x8*)(packLo + (size_t)(aStrip0 + s) * 1024);
        aHi[s][0] = pH[lane]; aHi[s][1] = pH[64 + lane];
        aLo[s][0] = pL[lane]; aLo[s][1] = pL[64 + lane];
    }

    // Per-strip family classification (rows sorted -> piecewise constant).
    int sLo[4], sHi[4], sUni[4];
#pragma unroll
    for (int s = 0; s < 4; s++) {
        int f0  = famSorted[rowBase + s * 16];
        int f15 = famSorted[rowBase + s * 16 + 15];
        sUni[s] = __builtin_amdgcn_readfirstlane((f0 == f15) ? 1 : 0);
        sLo[s]  = __builtin_amdgcn_readfirstlane(famLoHi[f0]);
        sHi[s]  = __builtin_amdgcn_readfirstlane(famLoHi[4 + f0]);
    }

    f32x4 mn[4], mx[4];
#pragma unroll
    for (int s = 0; s < 4; s++)
#pragma unroll
        for (int r = 0; r < 4; r++) { mn[s][r] = 1e30f; mx[s][r] = -1e30f; }

    const int jChunk0 = blockIdx.y * (B / NJ);
    const int jStrip0 = jChunk0 >> 4;
    const int NJT = (B / NJ) >> 4;  // 16 (even)

    auto loadB = [&](int jt, bf16x8& h0, bf16x8& h1, bf16x8& l0, bf16x8& l1) {
        const bf16x8* pBH = (const bf16x8*)(packHi + (size_t)(jStrip0 + jt) * 1024);
        const bf16x8* pBL = (const bf16x8*)(packLo + (size_t)(jStrip0 + jt) * 1024);
        h0 = pBH[lane]; h1 = pBH[64 + lane];
        l0 = pBL[lane]; l1 = pBL[64 + lane];
    };

    auto compute = [&](int jt, const bf16x8& bh0, const bf16x8& bh1,
                       const bf16x8& bl0, const bf16x8& bl1) {
        const int j0 = jChunk0 + jt * 16;
#pragma unroll
        for (int s = 0; s < 4; s++) {
            f32x4 acc = {0.f, 0.f, 0.f, 0.f};
            acc = __builtin_amdgcn_mfma_f32_16x16x32_bf16(aHi[s][0], bh0, acc, 0, 0, 0);
            acc = __builtin_amdgcn_mfma_f32_16x16x32_bf16(aHi[s][1], bh1, acc, 0, 0, 0);
            acc = __builtin_amdgcn_mfma_f32_16x16x32_bf16(aLo[s][0], bh0, acc, 0, 0, 0);
            acc = __builtin_amdgcn_mfma_f32_16x16x32_bf16(aLo[s][1], bh1, acc, 0, 0, 0);
            acc = __builtin_amdgcn_mfma_f32_16x16x32_bf16(aHi[s][0], bl0, acc, 0, 0, 0);
            acc = __builtin_amdgcn_mfma_f32_16x16x32_bf16(aHi[s][1], bl1, acc, 0, 0, 0);

            if (sUni[s] && j0 >= sLo[s] && j0 + 16 <= sHi[s]) {
                // tile fully same-family (diag dot==1 can never be the min)
#pragma unroll
                for (int r = 0; r < 4; r++) mn[s][r] = fminf(mn[s][r], acc[r]);
            } else if (sUni[s] && (j0 >= sHi[s] || j0 + 16 <= sLo[s])) {
                // tile fully different-family
#pragma unroll
                for (int r = 0; r < 4; r++) mx[s][r] = fmaxf(mx[s][r], acc[r]);
            } else {
                // boundary tile: per-element family compare
                int fj = famSorted[j0 + c];
                unsigned fi4 = *(const unsigned*)(famSorted + rowBase + s * 16 + g * 4);
#pragma unroll
                for (int r = 0; r < 4; r++) {
                    int fir = (int)((fi4 >> (8 * r)) & 255u);
                    bool same = (fir == fj);
                    float d = acc[r];
                    mn[s][r] = fminf(mn[s][r], same ? d : 1e30f);
                    mx[s][r] = fmaxf(mx[s][r], same ? -1e30f : d);
                }
            }
        }
    };

    // Software-pipelined sweep: register double-buffer, prefetch distance 1.
    bf16x8 ch0, ch1, cl0, cl1, nh0, nh1, nl0, nl1;
    loadB(0, ch0, ch1, cl0, cl1);
    for (int jt = 0; jt + 1 < NJT; jt += 2) {
        loadB(jt + 1, nh0, nh1, nl0, nl1);   // issue next-tile loads first
        compute(jt, ch0, ch1, cl0, cl1);
        if (jt + 2 < NJT) loadB(jt + 2, ch0, ch1, cl0, cl1);
        compute(jt + 1, nh0, nh1, nl0, nl1);
    }

    // Reduce across the 16 column-lanes (same g), then write per-row partials.
#pragma unroll
    for (int s = 0; s < 4; s++)
#pragma unroll
        for (int r = 0; r < 4; r++) {
            float mnv = mn[s][r], mxv = mx[s][r];
#pragma unroll
            for (int o = 8; o > 0; o >>= 1) {
                mnv = fminf(mnv, __shfl_xor(mnv, o, 64));
                mxv = fmaxf(mxv, __shfl_xor(mxv, o, 64));
            }
            if (c == 0) {
                int row = rowBase + s * 16 + g * 4 + r;  // sorted-row index
                pMin[(size_t)blockIdx.y * B + row] = mnv;
                pMax[(size_t)blockIdx.y * B + row] = mxv;
            }
        }
}

// ---------------- K4: per-row chunk combine + block partial sums ----------------
__global__ __launch_bounds__(256) void rowloss_kernel(const float* __restrict__ pMin,
                                                      const float* __restrict__ pMax,
                                                      float* __restrict__ partial, int B) {
    const int row = blockIdx.x * 256 + threadIdx.x;
    float mn = 1e30f, mx = -1e30f;
#pragma unroll 4
    for (int cn = 0; cn < NJ; cn++) {
        mn = fminf(mn, pMin[(size_t)cn * B + row]);
        mx = fmaxf(mx, pMax[(size_t)cn * B + row]);
    }
    float sum = 0.f, cnt = 0.f;
    if (mn < 1e29f && mx > -1e29f) {  // has same && has diff
        sum = fmaxf(mx - mn + MARGIN, 0.f);  // relu(d_pos - d_neg + margin)
        cnt = 1.f;
    }
#pragma unroll
    for (int o = 32; o > 0; o >>= 1) {
        sum += __shfl_xor(sum, o, 64);
        cnt += __shfl_xor(cnt, o, 64);
    }
    __shared__ float sS[4], sC[4];
    const int lane = threadIdx.x & 63, w = threadIdx.x >> 6;
    if (lane == 0) { sS[w] = sum; sC[w] = cnt; }
    __syncthreads();
    if (threadIdx.x == 0) {
        partial[blockIdx.x]      = sS[0] + sS[1] + sS[2] + sS[3];
        partial[64 + blockIdx.x] = sC[0] + sC[1] + sC[2] + sC[3];
    }
}

// ---------------- K5: deterministic final reduce ----------------
__global__ void final_kernel(const float* __restrict__ partial, float* __restrict__ out, int nb) {
    if (threadIdx.x == 0) {
        float S = 0.f, C = 0.f;
        for (int i = 0; i < nb; i++) { S += partial[i]; C += partial[64 + i]; }
        out[0] = S / fmaxf(C, 1.f);
    }
}

extern "C" void kernel_launch(void* const* d_in, const int* in_sizes, int n_in,
                              void* d_out, int out_size, void* d_ws, size_t ws_size,
                              hipStream_t stream) {
    const float* emb    = (const float*)d_in[0];
    const int*   labels = (const int*)d_in[1];
    const int B = in_sizes[1];  // 8192, D == 64

    char* base = (char*)d_ws;
    size_t off = 0;
    auto alloc = [&](size_t bytes) -> char* {
        char* p = base + off;
        off = (off + bytes + 255) & ~(size_t)255;
        return p;
    };
    int*           posOf     = (int*)alloc((size_t)B * 4);
    unsigned char* famSorted = (unsigned char*)alloc((size_t)B);
    int*           famLoHi   = (int*)alloc(32);
    short*         packHi    = (short*)alloc((size_t)B * 64 * 2);
    short*         packLo    = (short*)alloc((size_t)B * 64 * 2);
    float*         pMin      = (float*)alloc((size_t)NJ * B * 4);
    float*         pMax      = (float*)alloc((size_t)NJ * B * 4);
    float*         partial   = (float*)alloc(128 * 4);

    sort_kernel<<<1, 1024, 0, stream>>>(labels, posOf, famSorted, famLoHi, B);
    normpack_kernel<<<B / 4, 256, 0, stream>>>(emb, posOf, packHi, packLo, B);
    dim3 g3(B / 256, NJ);
    gemm_minmax_kernel<<<g3, 256, 0, stream>>>(packHi, packLo, famSorted, famLoHi, pMin, pMax, B);
    rowloss_kernel<<<B / 256, 256, 0, stream>>>(pMin, pMax, partial, B);
    final_kernel<<<1, 64, 0, stream>>>(partial, (float*)d_out, B / 256);
}

// Round 4
// 75.629 us; speedup vs baseline: 2.3056x; 2.3056x over previous
//
#include <hip/hip_runtime.h>
#include <math.h>

#define MARGIN 0.3f
#define NJ 64   // column chunks (grid.y)

typedef short bf16x8 __attribute__((ext_vector_type(8)));
typedef float f32x4 __attribute__((ext_vector_type(4)));

__device__ __forceinline__ unsigned short f2bf_rne(float x) {
    unsigned b = __float_as_uint(x);
    unsigned r = b + 0x7FFFu + ((b >> 16) & 1u);
    return (unsigned short)(r >> 16);
}
__device__ __forceinline__ float bf2f(unsigned short h) {
    return __uint_as_float(((unsigned)h) << 16);
}
// family table {0,1,2,1,3,3} packed 2 bits/entry
__device__ __forceinline__ int fam_of(int lbl) { return (0xF64 >> (2 * lbl)) & 3; }

// ---------------- K1: deterministic counting sort by family ----------------
// 1 block, 1024 threads, 8 rows/thread. Wave-level shfl scans; 3 barriers.
__global__ __launch_bounds__(1024) void sort_kernel(const int* __restrict__ labels,
                                                    int* __restrict__ posOf,
                                                    unsigned char* __restrict__ famSorted,
                                                    int* __restrict__ famLoHi, int B) {
    const int t = threadIdx.x;
    const int lane = t & 63, w = t >> 6;
    int lc[4] = {0, 0, 0, 0};
    int lf[8], lr[8];
#pragma unroll
    for (int j = 0; j < 8; j++) {
        int f = fam_of(labels[t * 8 + j]);
        lf[j] = f; lr[j] = lc[f]++;
    }
    // inclusive scan of per-thread counts across the wave, per family
    int inc[4];
#pragma unroll
    for (int f = 0; f < 4; f++) {
        int v = lc[f];
#pragma unroll
        for (int o = 1; o < 64; o <<= 1) {
            int u = __shfl_up(v, o, 64);
            if (lane >= o) v += u;
        }
        inc[f] = v;
    }
    __shared__ int waveTot[16][4], waveBase[16][4], famBase[4], famTotS[4];
    if (lane == 63)
#pragma unroll
        for (int f = 0; f < 4; f++) waveTot[w][f] = inc[f];
    __syncthreads();
    if (t < 64) {  // wave 0: scan 16 wave-totals for each of 4 families
        int f = t >> 4, ww = t & 15;
        int v = waveTot[ww][f];
#pragma unroll
        for (int o = 1; o < 16; o <<= 1) {
            int u = __shfl_up(v, o, 64);
            if ((t & 15) >= o) v += u;
        }
        waveBase[ww][f] = v - waveTot[ww][f];  // exclusive
        if (ww == 15) famTotS[f] = v;
    }
    __syncthreads();
    if (t == 0) {
        int b = 0;
#pragma unroll
        for (int f = 0; f < 4; f++) {
            famBase[f] = b; famLoHi[f] = b; b += famTotS[f]; famLoHi[4 + f] = b;
        }
    }
    __syncthreads();
    int base[4];
#pragma unroll
    for (int f = 0; f < 4; f++) base[f] = famBase[f] + waveBase[w][f] + (inc[f] - lc[f]);
#pragma unroll
    for (int j = 0; j < 8; j++) {
        int pos = base[lf[j]] + lr[j];
        posOf[t * 8 + j] = pos;
        famSorted[pos] = (unsigned char)lf[j];
    }
}

// ---------------- K2: normalize + bf16 hi/lo split + packed scatter ----------------
// pack layout (bf16 elems): idx = strip*1024 + (k>>3)*128 + (pos&15)*8 + (k&7)
// so lane l reads its MFMA fragment as one coalesced 16B load at strip*1024 + l*8.
__global__ __launch_bounds__(256) void normpack_kernel(const float* __restrict__ emb,
                                                       const int* __restrict__ posOf,
                                                       short* __restrict__ packHi,
                                                       short* __restrict__ packLo, int B) {
    const int lane = threadIdx.x & 63;
    const int wid  = threadIdx.x >> 6;
    const int row  = blockIdx.x * 4 + wid;
    float x = emb[(size_t)row * 64 + lane];
    float ss = x * x;
#pragma unroll
    for (int o = 32; o > 0; o >>= 1) ss += __shfl_xor(ss, o, 64);
    float n = fmaxf(sqrtf(ss), 1e-12f);
    float v = x / n;
    unsigned short h = f2bf_rne(v);
    float lo = v - bf2f(h);
    unsigned short l = f2bf_rne(lo);
    int pos = posOf[row];
    size_t idx = (size_t)(pos >> 4) * 1024 + (size_t)(lane >> 3) * 128 + (size_t)(pos & 15) * 8 + (lane & 7);
    packHi[idx] = (short)h;
    packLo[idx] = (short)l;
}

// ---------------- K3: MFMA GEMM + masked min/max (no LDS, macro-pipelined) ----------------
// 4 waves/block, 64 rows/wave (4 strips of 16), chunk of B/NJ cols.
// Prefetch via macros on NAMED variables: nothing address-taken -> no scratch.
#define LOADB(H0, H1, L0, L1, JT)                                                   \
    do {                                                                            \
        const bf16x8* pBH_ = (const bf16x8*)(packHi + (size_t)(jStrip0 + (JT)) * 1024); \
        const bf16x8* pBL_ = (const bf16x8*)(packLo + (size_t)(jStrip0 + (JT)) * 1024); \
        H0 = pBH_[lane]; H1 = pBH_[64 + lane];                                      \
        L0 = pBL_[lane]; L1 = pBL_[64 + lane];                                      \
    } while (0)

#define COMPUTE(BH0, BH1, BL0, BL1, JT)                                             \
    do {                                                                            \
        const int j0_ = jChunk0 + (JT) * 16;                                        \
        _Pragma("unroll")                                                           \
        for (int s = 0; s < 4; s++) {                                               \
            f32x4 acc = {0.f, 0.f, 0.f, 0.f};                                       \
            acc = __builtin_amdgcn_mfma_f32_16x16x32_bf16(aHi[s][0], BH0, acc, 0, 0, 0); \
            acc = __builtin_amdgcn_mfma_f32_16x16x32_bf16(aHi[s][1], BH1, acc, 0, 0, 0); \
            acc = __builtin_amdgcn_mfma_f32_16x16x32_bf16(aLo[s][0], BH0, acc, 0, 0, 0); \
            acc = __builtin_amdgcn_mfma_f32_16x16x32_bf16(aLo[s][1], BH1, acc, 0, 0, 0); \
            acc = __builtin_amdgcn_mfma_f32_16x16x32_bf16(aHi[s][0], BL0, acc, 0, 0, 0); \
            acc = __builtin_amdgcn_mfma_f32_16x16x32_bf16(aHi[s][1], BL1, acc, 0, 0, 0); \
            if (sUni[s] && j0_ >= sLo[s] && j0_ + 16 <= sHi[s]) {                   \
                _Pragma("unroll")                                                   \
                for (int r = 0; r < 4; r++) mn[s][r] = fminf(mn[s][r], acc[r]);     \
            } else if (sUni[s] && (j0_ >= sHi[s] || j0_ + 16 <= sLo[s])) {          \
                _Pragma("unroll")                                                   \
                for (int r = 0; r < 4; r++) mx[s][r] = fmaxf(mx[s][r], acc[r]);     \
            } else {                                                                \
                int fj_ = famSorted[j0_ + c];                                       \
                unsigned fi4_ = *(const unsigned*)(famSorted + rowBase + s * 16 + g * 4); \
                _Pragma("unroll")                                                   \
                for (int r = 0; r < 4; r++) {                                       \
                    int fir_ = (int)((fi4_ >> (8 * r)) & 255u);                     \
                    bool same_ = (fir_ == fj_);                                     \
                    float d_ = acc[r];                                              \
                    mn[s][r] = fminf(mn[s][r], same_ ? d_ : 1e30f);                 \
                    mx[s][r] = fmaxf(mx[s][r], same_ ? -1e30f : d_);                \
                }                                                                   \
            }                                                                       \
        }                                                                           \
    } while (0)

__global__ __launch_bounds__(256) void gemm_minmax_kernel(
    const short* __restrict__ packHi, const short* __restrict__ packLo,
    const unsigned char* __restrict__ famSorted, const int* __restrict__ famLoHi,
    float* __restrict__ pMin, float* __restrict__ pMax, int B) {
    const int lane = threadIdx.x & 63;
    const int wid  = threadIdx.x >> 6;
    const int g = lane >> 4;
    const int c = lane & 15;
    const int rowBase = blockIdx.x * 256 + wid * 64;
    const int aStrip0 = rowBase >> 4;

    // A fragments: 4 strips x 2 k-windows x (hi,lo). 64 VGPRs, resident all sweep.
    bf16x8 aHi[4][2], aLo[4][2];
#pragma unroll
    for (int s = 0; s < 4; s++) {
        const bf16x8* pH = (const bf16x8*)(packHi + (size_t)(aStrip0 + s) * 1024);
        const bf16x8* pL = (const bf16x8*)(packLo + (size_t)(aStrip0 + s) * 1024);
        aHi[s][0] = pH[lane]; aHi[s][1] = pH[64 + lane];
        aLo[s][0] = pL[lane]; aLo[s][1] = pL[64 + lane];
    }

    // Per-strip family classification (rows sorted -> piecewise constant).
    int sLo[4], sHi[4], sUni[4];
#pragma unroll
    for (int s = 0; s < 4; s++) {
        int f0  = famSorted[rowBase + s * 16];
        int f15 = famSorted[rowBase + s * 16 + 15];
        sUni[s] = __builtin_amdgcn_readfirstlane((f0 == f15) ? 1 : 0);
        sLo[s]  = __builtin_amdgcn_readfirstlane(famLoHi[f0]);
        sHi[s]  = __builtin_amdgcn_readfirstlane(famLoHi[4 + f0]);
    }

    f32x4 mn[4], mx[4];
#pragma unroll
    for (int s = 0; s < 4; s++)
#pragma unroll
        for (int r = 0; r < 4; r++) { mn[s][r] = 1e30f; mx[s][r] = -1e30f; }

    const int jChunk0 = blockIdx.y * (B / NJ);
    const int jStrip0 = jChunk0 >> 4;
    const int NJT = (B / NJ) >> 4;  // 8 (even)

    // Software-pipelined sweep, prefetch distance 1, named-variable double buffer.
    bf16x8 ch0, ch1, cl0, cl1, nh0, nh1, nl0, nl1;
    LOADB(ch0, ch1, cl0, cl1, 0);
    for (int jt = 0; jt < NJT; jt += 2) {
        if (jt + 1 < NJT) LOADB(nh0, nh1, nl0, nl1, jt + 1);
        COMPUTE(ch0, ch1, cl0, cl1, jt);
        if (jt + 2 < NJT) LOADB(ch0, ch1, cl0, cl1, jt + 2);
        if (jt + 1 < NJT) COMPUTE(nh0, nh1, nl0, nl1, jt + 1);
    }

    // Reduce across the 16 column-lanes (same g), then write per-row partials.
#pragma unroll
    for (int s = 0; s < 4; s++)
#pragma unroll
        for (int r = 0; r < 4; r++) {
            float mnv = mn[s][r], mxv = mx[s][r];
#pragma unroll
            for (int o = 8; o > 0; o >>= 1) {
                mnv = fminf(mnv, __shfl_xor(mnv, o, 64));
                mxv = fmaxf(mxv, __shfl_xor(mxv, o, 64));
            }
            if (c == 0) {
                int row = rowBase + s * 16 + g * 4 + r;  // sorted-row index
                pMin[(size_t)blockIdx.y * B + row] = mnv;
                pMax[(size_t)blockIdx.y * B + row] = mxv;
            }
        }
}

// ---------------- K4: per-row chunk combine + block partial sums ----------------
__global__ __launch_bounds__(256) void rowloss_kernel(const float* __restrict__ pMin,
                                                      const float* __restrict__ pMax,
                                                      float* __restrict__ partial, int B) {
    const int row = blockIdx.x * 256 + threadIdx.x;
    float mn = 1e30f, mx = -1e30f;
#pragma unroll 4
    for (int cn = 0; cn < NJ; cn++) {
        mn = fminf(mn, pMin[(size_t)cn * B + row]);
        mx = fmaxf(mx, pMax[(size_t)cn * B + row]);
    }
    float sum = 0.f, cnt = 0.f;
    if (mn < 1e29f && mx > -1e29f) {  // has same && has diff
        sum = fmaxf(mx - mn + MARGIN, 0.f);  // relu(d_pos - d_neg + margin)
        cnt = 1.f;
    }
#pragma unroll
    for (int o = 32; o > 0; o >>= 1) {
        sum += __shfl_xor(sum, o, 64);
        cnt += __shfl_xor(cnt, o, 64);
    }
    __shared__ float sS[4], sC[4];
    const int lane = threadIdx.x & 63, w = threadIdx.x >> 6;
    if (lane == 0) { sS[w] = sum; sC[w] = cnt; }
    __syncthreads();
    if (threadIdx.x == 0) {
        partial[blockIdx.x]      = sS[0] + sS[1] + sS[2] + sS[3];
        partial[64 + blockIdx.x] = sC[0] + sC[1] + sC[2] + sC[3];
    }
}

// ---------------- K5: deterministic final reduce ----------------
__global__ void final_kernel(const float* __restrict__ partial, float* __restrict__ out, int nb) {
    if (threadIdx.x == 0) {
        float S = 0.f, C = 0.f;
        for (int i = 0; i < nb; i++) { S += partial[i]; C += partial[64 + i]; }
        out[0] = S / fmaxf(C, 1.f);
    }
}

extern "C" void kernel_launch(void* const* d_in, const int* in_sizes, int n_in,
                              void* d_out, int out_size, void* d_ws, size_t ws_size,
                              hipStream_t stream) {
    const float* emb    = (const float*)d_in[0];
    const int*   labels = (const int*)d_in[1];
    const int B = in_sizes[1];  // 8192, D == 64

    char* base = (char*)d_ws;
    size_t off = 0;
    auto alloc = [&](size_t bytes) -> char* {
        char* p = base + off;
        off = (off + bytes + 255) & ~(size_t)255;
        return p;
    };
    int*           posOf     = (int*)alloc((size_t)B * 4);
    unsigned char* famSorted = (unsigned char*)alloc((size_t)B);
    int*           famLoHi   = (int*)alloc(32);
    short*         packHi    = (short*)alloc((size_t)B * 64 * 2);
    short*         packLo    = (short*)alloc((size_t)B * 64 * 2);
    float*         pMin      = (float*)alloc((size_t)NJ * B * 4);
    float*         pMax      = (float*)alloc((size_t)NJ * B * 4);
    float*         partial   = (float*)alloc(128 * 4);

    sort_kernel<<<1, 1024, 0, stream>>>(labels, posOf, famSorted, famLoHi, B);
    normpack_kernel<<<B / 4, 256, 0, stream>>>(emb, posOf, packHi, packLo, B);
    dim3 g3(B / 256, NJ);
    gemm_minmax_kernel<<<g3, 256, 0, stream>>>(packHi, packLo, famSorted, famLoHi, pMin, pMax, B);
    rowloss_kernel<<<B / 256, 256, 0, stream>>>(pMin, pMax, partial, B);
    final_kernel<<<1, 64, 0, stream>>>(partial, (float*)d_out, B / 256);
}

// Round 5
// 65.791 us; speedup vs baseline: 2.6504x; 1.1495x over previous
//
#include <hip/hip_runtime.h>
#include <math.h>

#define MARGIN 0.3f
#define NJ 32   // column chunks (grid.y)

typedef short bf16x8 __attribute__((ext_vector_type(8)));
typedef float f32x4 __attribute__((ext_vector_type(4)));

__device__ __forceinline__ unsigned short f2bf_rne(float x) {
    unsigned b = __float_as_uint(x);
    unsigned r = b + 0x7FFFu + ((b >> 16) & 1u);
    return (unsigned short)(r >> 16);
}
__device__ __forceinline__ float bf2f(unsigned short h) {
    return __uint_as_float(((unsigned)h) << 16);
}
// family table {0,1,2,1,3,3} packed 2 bits/entry
__device__ __forceinline__ int fam_of(int lbl) { return (0xF64 >> (2 * lbl)) & 3; }

// ---------------- K1: deterministic counting sort by family ----------------
// 1 block, 1024 threads, 8 rows/thread. Wave-level shfl scans; 3 barriers.
__global__ __launch_bounds__(1024) void sort_kernel(const int* __restrict__ labels,
                                                    int* __restrict__ posOf,
                                                    unsigned char* __restrict__ famSorted,
                                                    int* __restrict__ famLoHi, int B) {
    const int t = threadIdx.x;
    const int lane = t & 63, w = t >> 6;
    int lc[4] = {0, 0, 0, 0};
    int lf[8], lr[8];
#pragma unroll
    for (int j = 0; j < 8; j++) {
        int f = fam_of(labels[t * 8 + j]);
        lf[j] = f; lr[j] = lc[f]++;
    }
    // inclusive scan of per-thread counts across the wave, per family
    int inc[4];
#pragma unroll
    for (int f = 0; f < 4; f++) {
        int v = lc[f];
#pragma unroll
        for (int o = 1; o < 64; o <<= 1) {
            int u = __shfl_up(v, o, 64);
            if (lane >= o) v += u;
        }
        inc[f] = v;
    }
    __shared__ int waveTot[16][4], waveBase[16][4], famBase[4], famTotS[4];
    if (lane == 63)
#pragma unroll
        for (int f = 0; f < 4; f++) waveTot[w][f] = inc[f];
    __syncthreads();
    if (t < 64) {  // wave 0: scan 16 wave-totals for each of 4 families
        int f = t >> 4, ww = t & 15;
        int v = waveTot[ww][f];
#pragma unroll
        for (int o = 1; o < 16; o <<= 1) {
            int u = __shfl_up(v, o, 64);
            if ((t & 15) >= o) v += u;
        }
        waveBase[ww][f] = v - waveTot[ww][f];  // exclusive
        if (ww == 15) famTotS[f] = v;
    }
    __syncthreads();
    if (t == 0) {
        int b = 0;
#pragma unroll
        for (int f = 0; f < 4; f++) {
            famBase[f] = b; famLoHi[f] = b; b += famTotS[f]; famLoHi[4 + f] = b;
        }
    }
    __syncthreads();
    int base[4];
#pragma unroll
    for (int f = 0; f < 4; f++) base[f] = famBase[f] + waveBase[w][f] + (inc[f] - lc[f]);
#pragma unroll
    for (int j = 0; j < 8; j++) {
        int pos = base[lf[j]] + lr[j];
        posOf[t * 8 + j] = pos;
        famSorted[pos] = (unsigned char)lf[j];
    }
}

// ---------------- K2: normalize + bf16 hi/lo split + packed scatter ----------------
// pack layout (bf16 elems): idx = strip*1024 + (k>>3)*128 + (pos&15)*8 + (k&7)
// so lane l reads its MFMA fragment as one coalesced 16B load at strip*1024 + l*8.
__global__ __launch_bounds__(256) void normpack_kernel(const float* __restrict__ emb,
                                                       const int* __restrict__ posOf,
                                                       short* __restrict__ packHi,
                                                       short* __restrict__ packLo, int B) {
    const int lane = threadIdx.x & 63;
    const int wid  = threadIdx.x >> 6;
    const int row  = blockIdx.x * 4 + wid;
    float x = emb[(size_t)row * 64 + lane];
    float ss = x * x;
#pragma unroll
    for (int o = 32; o > 0; o >>= 1) ss += __shfl_xor(ss, o, 64);
    float n = fmaxf(sqrtf(ss), 1e-12f);
    float v = x / n;
    unsigned short h = f2bf_rne(v);
    float lo = v - bf2f(h);
    unsigned short l = f2bf_rne(lo);
    int pos = posOf[row];
    size_t idx = (size_t)(pos >> 4) * 1024 + (size_t)(lane >> 3) * 128 + (size_t)(pos & 15) * 8 + (lane & 7);
    packHi[idx] = (short)h;
    packLo[idx] = (short)l;
}

// ---------------- K3: MFMA GEMM + masked min/max (no LDS, macro-pipelined) ----------------
// 4 waves/block, 64 rows/wave (4 strips of 16), chunk of B/NJ cols.
// Prefetch via macros on NAMED variables: nothing address-taken -> no scratch.
#define LOADB(H0, H1, L0, L1, JT)                                                   \
    do {                                                                            \
        const bf16x8* pBH_ = (const bf16x8*)(packHi + (size_t)(jStrip0 + (JT)) * 1024); \
        const bf16x8* pBL_ = (const bf16x8*)(packLo + (size_t)(jStrip0 + (JT)) * 1024); \
        H0 = pBH_[lane]; H1 = pBH_[64 + lane];                                      \
        L0 = pBL_[lane]; L1 = pBL_[64 + lane];                                      \
    } while (0)

#define COMPUTE(BH0, BH1, BL0, BL1, JT)                                             \
    do {                                                                            \
        const int j0_ = jChunk0 + (JT) * 16;                                        \
        _Pragma("unroll")                                                           \
        for (int s = 0; s < 4; s++) {                                               \
            f32x4 acc = {0.f, 0.f, 0.f, 0.f};                                       \
            acc = __builtin_amdgcn_mfma_f32_16x16x32_bf16(aHi[s][0], BH0, acc, 0, 0, 0); \
            acc = __builtin_amdgcn_mfma_f32_16x16x32_bf16(aHi[s][1], BH1, acc, 0, 0, 0); \
            acc = __builtin_amdgcn_mfma_f32_16x16x32_bf16(aLo[s][0], BH0, acc, 0, 0, 0); \
            acc = __builtin_amdgcn_mfma_f32_16x16x32_bf16(aLo[s][1], BH1, acc, 0, 0, 0); \
            acc = __builtin_amdgcn_mfma_f32_16x16x32_bf16(aHi[s][0], BL0, acc, 0, 0, 0); \
            acc = __builtin_amdgcn_mfma_f32_16x16x32_bf16(aHi[s][1], BL1, acc, 0, 0, 0); \
            if (sUni[s] && j0_ >= sLo[s] && j0_ + 16 <= sHi[s]) {                   \
                _Pragma("unroll")                                                   \
                for (int r = 0; r < 4; r++) mn[s][r] = fminf(mn[s][r], acc[r]);     \
            } else if (sUni[s] && (j0_ >= sHi[s] || j0_ + 16 <= sLo[s])) {          \
                _Pragma("unroll")                                                   \
                for (int r = 0; r < 4; r++) mx[s][r] = fmaxf(mx[s][r], acc[r]);     \
            } else {                                                                \
                int fj_ = famSorted[j0_ + c];                                       \
                unsigned fi4_ = *(const unsigned*)(famSorted + rowBase + s * 16 + g * 4); \
                _Pragma("unroll")                                                   \
                for (int r = 0; r < 4; r++) {                                       \
                    int fir_ = (int)((fi4_ >> (8 * r)) & 255u);                     \
                    bool same_ = (fir_ == fj_);                                     \
                    float d_ = acc[r];                                              \
                    mn[s][r] = fminf(mn[s][r], same_ ? d_ : 1e30f);                 \
                    mx[s][r] = fmaxf(mx[s][r], same_ ? -1e30f : d_);                \
                }                                                                   \
            }                                                                       \
        }                                                                           \
    } while (0)

__global__ __launch_bounds__(256, 2) void gemm_minmax_kernel(
    const short* __restrict__ packHi, const short* __restrict__ packLo,
    const unsigned char* __restrict__ famSorted, const int* __restrict__ famLoHi,
    float* __restrict__ pMin, float* __restrict__ pMax, int B) {
    const int lane = threadIdx.x & 63;
    const int wid  = threadIdx.x >> 6;
    const int g = lane >> 4;
    const int c = lane & 15;
    const int rowBase = blockIdx.x * 256 + wid * 64;
    const int aStrip0 = rowBase >> 4;

    // A fragments: 4 strips x 2 k-windows x (hi,lo). 64 VGPRs, resident all sweep.
    bf16x8 aHi[4][2], aLo[4][2];
#pragma unroll
    for (int s = 0; s < 4; s++) {
        const bf16x8* pH = (const bf16x8*)(packHi + (size_t)(aStrip0 + s) * 1024);
        const bf16x8* pL = (const bf16x8*)(packLo + (size_t)(aStrip0 + s) * 1024);
        aHi[s][0] = pH[lane]; aHi[s][1] = pH[64 + lane];
        aLo[s][0] = pL[lane]; aLo[s][1] = pL[64 + lane];
    }

    // Per-strip family classification (rows sorted -> piecewise constant).
    int sLo[4], sHi[4], sUni[4];
#pragma unroll
    for (int s = 0; s < 4; s++) {
        int f0  = famSorted[rowBase + s * 16];
        int f15 = famSorted[rowBase + s * 16 + 15];
        sUni[s] = __builtin_amdgcn_readfirstlane((f0 == f15) ? 1 : 0);
        sLo[s]  = __builtin_amdgcn_readfirstlane(famLoHi[f0]);
        sHi[s]  = __builtin_amdgcn_readfirstlane(famLoHi[4 + f0]);
    }

    f32x4 mn[4], mx[4];
#pragma unroll
    for (int s = 0; s < 4; s++)
#pragma unroll
        for (int r = 0; r < 4; r++) { mn[s][r] = 1e30f; mx[s][r] = -1e30f; }

    const int jChunk0 = blockIdx.y * (B / NJ);
    const int jStrip0 = jChunk0 >> 4;
    const int NJT = (B / NJ) >> 4;  // 16 (even)

    // Software-pipelined sweep, prefetch distance 1, named-variable double buffer.
    bf16x8 ch0, ch1, cl0, cl1, nh0, nh1, nl0, nl1;
    LOADB(ch0, ch1, cl0, cl1, 0);
    for (int jt = 0; jt < NJT; jt += 2) {
        if (jt + 1 < NJT) LOADB(nh0, nh1, nl0, nl1, jt + 1);
        COMPUTE(ch0, ch1, cl0, cl1, jt);
        if (jt + 2 < NJT) LOADB(ch0, ch1, cl0, cl1, jt + 2);
        if (jt + 1 < NJT) COMPUTE(nh0, nh1, nl0, nl1, jt + 1);
    }

    // Reduce across the 16 column-lanes (same g), then write per-row partials.
#pragma unroll
    for (int s = 0; s < 4; s++)
#pragma unroll
        for (int r = 0; r < 4; r++) {
            float mnv = mn[s][r], mxv = mx[s][r];
#pragma unroll
            for (int o = 8; o > 0; o >>= 1) {
                mnv = fminf(mnv, __shfl_xor(mnv, o, 64));
                mxv = fmaxf(mxv, __shfl_xor(mxv, o, 64));
            }
            if (c == 0) {
                int row = rowBase + s * 16 + g * 4 + r;  // sorted-row index
                pMin[(size_t)blockIdx.y * B + row] = mnv;
                pMax[(size_t)blockIdx.y * B + row] = mxv;
            }
        }
}

// ---------------- K4: per-row chunk combine + block partial sums ----------------
__global__ __launch_bounds__(256) void rowloss_kernel(const float* __restrict__ pMin,
                                                      const float* __restrict__ pMax,
                                                      float* __restrict__ partial, int B) {
    const int row = blockIdx.x * 256 + threadIdx.x;
    float mn = 1e30f, mx = -1e30f;
#pragma unroll 4
    for (int cn = 0; cn < NJ; cn++) {
        mn = fminf(mn, pMin[(size_t)cn * B + row]);
        mx = fmaxf(mx, pMax[(size_t)cn * B + row]);
    }
    float sum = 0.f, cnt = 0.f;
    if (mn < 1e29f && mx > -1e29f) {  // has same && has diff
        sum = fmaxf(mx - mn + MARGIN, 0.f);  // relu(d_pos - d_neg + margin)
        cnt = 1.f;
    }
#pragma unroll
    for (int o = 32; o > 0; o >>= 1) {
        sum += __shfl_xor(sum, o, 64);
        cnt += __shfl_xor(cnt, o, 64);
    }
    __shared__ float sS[4], sC[4];
    const int lane = threadIdx.x & 63, w = threadIdx.x >> 6;
    if (lane == 0) { sS[w] = sum; sC[w] = cnt; }
    __syncthreads();
    if (threadIdx.x == 0) {
        partial[blockIdx.x]      = sS[0] + sS[1] + sS[2] + sS[3];
        partial[64 + blockIdx.x] = sC[0] + sC[1] + sC[2] + sC[3];
    }
}

// ---------------- K5: deterministic final reduce ----------------
__global__ void final_kernel(const float* __restrict__ partial, float* __restrict__ out, int nb) {
    if (threadIdx.x == 0) {
        float S = 0.f, C = 0.f;
        for (int i = 0; i < nb; i++) { S += partial[i]; C += partial[64 + i]; }
        out[0] = S / fmaxf(C, 1.f);
    }
}

extern "C" void kernel_launch(void* const* d_in, const int* in_sizes, int n_in,
                              void* d_out, int out_size, void* d_ws, size_t ws_size,
                              hipStream_t stream) {
    const float* emb    = (const float*)d_in[0];
    const int*   labels = (const int*)d_in[1];
    const int B = in_sizes[1];  // 8192, D == 64

    char* base = (char*)d_ws;
    size_t off = 0;
    auto alloc = [&](size_t bytes) -> char* {
        char* p = base + off;
        off = (off + bytes + 255) & ~(size_t)255;
        return p;
    };
    int*           posOf     = (int*)alloc((size_t)B * 4);
    unsigned char* famSorted = (unsigned char*)alloc((size_t)B);
    int*           famLoHi   = (int*)alloc(32);
    short*         packHi    = (short*)alloc((size_t)B * 64 * 2);
    short*         packLo    = (short*)alloc((size_t)B * 64 * 2);
    float*         pMin      = (float*)alloc((size_t)NJ * B * 4);
    float*         pMax      = (float*)alloc((size_t)NJ * B * 4);
    float*         partial   = (float*)alloc(128 * 4);

    sort_kernel<<<1, 1024, 0, stream>>>(labels, posOf, famSorted, famLoHi, B);
    normpack_kernel<<<B / 4, 256, 0, stream>>>(emb, posOf, packHi, packLo, B);
    dim3 g3(B / 256, NJ);
    gemm_minmax_kernel<<<g3, 256, 0, stream>>>(packHi, packLo, famSorted, famLoHi, pMin, pMax, B);
    rowloss_kernel<<<B / 256, 256, 0, stream>>>(pMin, pMax, partial, B);
    final_kernel<<<1, 64, 0, stream>>>(partial, (float*)d_out, B / 256);
}